// Round 5
// baseline (538.820 us; speedup 1.0000x reference)
//
#include <hip/hip_runtime.h>
#include <hip/hip_bf16.h>
#include <cstdint>

#define M_ROWS 131072
#define D_DIM  256
#define K_CL   512

typedef __attribute__((ext_vector_type(4))) float  f4;
typedef __attribute__((ext_vector_type(8))) short  bfrag;   // 8 bf16 (4 VGPRs)
typedef __attribute__((ext_vector_type(4))) float  ffrag;   // 4 f32 acc

#define MFMA16(A,B,C) __builtin_amdgcn_mfma_f32_16x16x32_bf16((A),(B),(C),0,0,0)

__device__ __forceinline__ ffrag fzero() {
    ffrag z;
    z[0] = 0.f; z[1] = 0.f; z[2] = 0.f; z[3] = 0.f;
    return z;
}

__device__ __forceinline__ unsigned short f2bf(float f) {
    unsigned int u = __float_as_uint(f);
    u += 0x7FFFu + ((u >> 16) & 1u);          // round-to-nearest-even
    return (unsigned short)(u >> 16);
}
__device__ __forceinline__ float bf2f(unsigned short u) {
    return __uint_as_float(((unsigned int)u) << 16);
}

// ---------------------------------------------------------------------------
// Prep: cluster_center f32 [512][256] -> Cb bf16 [512][256], Ct bf16 [256][512],
// c_sq[512] (sum of squares of the bf16-rounded values, f32 accum).
// ---------------------------------------------------------------------------
__global__ void prep_kernel(const float* __restrict__ C,
                            unsigned short* __restrict__ Cb,
                            unsigned short* __restrict__ Ct,
                            float* __restrict__ csq)
{
    __shared__ unsigned short lds[64 * 264];
    const int tid = threadIdx.x;          // 256 threads
    const int kb  = blockIdx.x * 64;      // 8 blocks
    const int r   = tid >> 2;             // local k row 0..63
    const int q   = tid & 3;              // 4 threads per row

    const float* cr = C + (size_t)(kb + r) * D_DIM;
    float s = 0.f;
    #pragma unroll
    for (int i = 0; i < 16; ++i) {
        const int j = q * 16 + i;         // float4 index 0..63
        f4 v = *(const f4*)(cr + j * 4);
        unsigned short u0 = f2bf(v[0]), u1 = f2bf(v[1]), u2 = f2bf(v[2]), u3 = f2bf(v[3]);
        *(ushort4*)(Cb + (size_t)(kb + r) * D_DIM + j * 4) = make_ushort4(u0, u1, u2, u3);
        *(ushort4*)(lds + r * 264 + j * 4)                  = make_ushort4(u0, u1, u2, u3);
        float f0 = bf2f(u0), f1 = bf2f(u1), f2_ = bf2f(u2), f3 = bf2f(u3);
        s += f0 * f0 + f1 * f1 + f2_ * f2_ + f3 * f3;
    }
    s += __shfl_xor(s, 1, 64);
    s += __shfl_xor(s, 2, 64);
    if (q == 0) csq[kb + r] = s;
    __syncthreads();

    // transposed copy: thread tid = d (0..255), contiguous 64 k's
    #pragma unroll
    for (int c = 0; c < 16; ++c) {
        ushort4 p = make_ushort4(lds[(c * 4 + 0) * 264 + tid],
                                 lds[(c * 4 + 1) * 264 + tid],
                                 lds[(c * 4 + 2) * 264 + tid],
                                 lds[(c * 4 + 3) * 264 + tid]);
        *(ushort4*)(Ct + (size_t)tid * K_CL + kb + c * 4) = p;
    }
}

// ---------------------------------------------------------------------------
// Fused, barrier-free: one wave (64 threads) owns 16 rows end-to-end.
// Swapped-operand MFMA => lane holds (m=cl, 4 consecutive k-cols) => all
// global stores are dwordx4. Cross-lane exchange via private LDS (no barriers).
// ---------------------------------------------------------------------------
__global__ __launch_bounds__(64, 2)
void fused_kernel(const float* __restrict__ x,
                  const float* __restrict__ lnw,
                  const float* __restrict__ lnb,
                  const unsigned short* __restrict__ Cb,
                  const unsigned short* __restrict__ Ct,
                  const float* __restrict__ csq,
                  float* __restrict__ out0,   // x_distance  [M][512]
                  float* __restrict__ out1,   // assign      [M][512]
                  float* __restrict__ out2)   // x_rec       [M][256]
{
    __shared__ __align__(16) char smem[18560];
    // [0,16384): xn bf16 [16][264] (8448B)  UNION  as bf16 [16][512] XOR-swizzled
    float* csq_s = (float*)(smem + 16384);    // [512]
    float* xsq_s = (float*)(smem + 18432);    // [16]

    const int l   = threadIdx.x;     // 0..63
    const int g   = l >> 4;          // 16-lane group 0..3
    const int cl  = l & 15;
    const int m0  = blockIdx.x * 16;
    const int row = l >> 2;          // LN row 0..15
    const int sub = l & 3;           // LN quarter

#define LOADB(BUF, NT) {                                                        \
    const unsigned short* bp_ = Cb + ((NT) * 16 + cl) * D_DIM + g * 8;          \
    _Pragma("unroll")                                                           \
    for (int i_ = 0; i_ < 8; ++i_) (BUF)[i_] = *(const bfrag*)(bp_ + i_ * 32); }

#define TILE1(BUF, NT) {                                                        \
    acc[NT] = MFMA16((BUF)[0], xnf[0], fzero());                                \
    _Pragma("unroll")                                                           \
    for (int i_ = 1; i_ < 8; ++i_)                                              \
        acc[NT] = MFMA16((BUF)[i_], xnf[i_], acc[NT]); }

#define LOADC(BUF, NT) {                                                        \
    const unsigned short* cp_ = Ct + ((NT) * 16 + cl) * K_CL + g * 8;           \
    _Pragma("unroll")                                                           \
    for (int i_ = 0; i_ < 16; ++i_) (BUF)[i_] = *(const bfrag*)(cp_ + i_ * 32); }

#define TILE2(BUF, NT) {                                                        \
    ffrag p_ = MFMA16((BUF)[0], asf[0], fzero());                               \
    ffrag q_ = MFMA16((BUF)[1], asf[1], fzero());                               \
    _Pragma("unroll")                                                           \
    for (int i_ = 1; i_ < 8; ++i_) {                                            \
        p_ = MFMA16((BUF)[2 * i_],     asf[2 * i_],     p_);                    \
        q_ = MFMA16((BUF)[2 * i_ + 1], asf[2 * i_ + 1], q_); }                  \
    f4 rv_;                                                                     \
    rv_[0] = p_[0] + q_[0]; rv_[1] = p_[1] + q_[1];                             \
    rv_[2] = p_[2] + q_[2]; rv_[3] = p_[3] + q_[3];                             \
    *(f4*)(out2 + (size_t)(m0 + cl) * D_DIM + (NT) * 16 + g * 4) = rv_; }

    // ---- issue x loads (HBM, longest latency) ----
    f4 xv[16];
    {
        const float* xr = x + (size_t)(m0 + row) * D_DIM + sub * 4;
        #pragma unroll
        for (int i = 0; i < 16; ++i) xv[i] = *(const f4*)(xr + i * 16);
    }

    // ---- prefetch GEMM1 A-tiles 0,1 (no barrier will drain these) ----
    bfrag b0[8], b1[8];
    LOADB(b0, 0);
    LOADB(b1, 1);

    // ---- stage csq into LDS (wave-private block) ----
    {
        f4 c0 = *(const f4*)(csq + l * 8);
        f4 c1 = *(const f4*)(csq + l * 8 + 4);
        *(f4*)(csq_s + l * 8)     = c0;
        *(f4*)(csq_s + l * 8 + 4) = c1;
    }

    // ---- LayerNorm (4 lanes per row) ----
    {
        float sum = 0.f, ss = 0.f;
        #pragma unroll
        for (int i = 0; i < 16; ++i)
            #pragma unroll
            for (int c = 0; c < 4; ++c) { float v = xv[i][c]; sum += v; ss += v * v; }
        sum += __shfl_xor(sum, 1, 64);  ss += __shfl_xor(ss, 1, 64);
        sum += __shfl_xor(sum, 2, 64);  ss += __shfl_xor(ss, 2, 64);
        const float mean = sum * (1.0f / 256.0f);
        float var = ss * (1.0f / 256.0f) - mean * mean;
        var = fmaxf(var, 0.0f);
        const float inv = 1.0f / (sqrtf(var) + 1e-5f);

        float xsq = 0.f;
        #pragma unroll
        for (int i = 0; i < 16; ++i) {
            f4 wv = *(const f4*)(lnw + sub * 4 + i * 16);
            f4 bv = *(const f4*)(lnb + sub * 4 + i * 16);
            float a0 = (xv[i][0] - mean) * inv * wv[0] + bv[0];
            float a1 = (xv[i][1] - mean) * inv * wv[1] + bv[1];
            float a2 = (xv[i][2] - mean) * inv * wv[2] + bv[2];
            float a3 = (xv[i][3] - mean) * inv * wv[3] + bv[3];
            unsigned short u0 = f2bf(a0), u1 = f2bf(a1), u2 = f2bf(a2), u3 = f2bf(a3);
            float c0 = bf2f(u0), c1 = bf2f(u1), c2 = bf2f(u2), c3 = bf2f(u3);
            xsq += c0 * c0 + c1 * c1 + c2 * c2 + c3 * c3;
            *(ushort4*)(smem + row * 528 + sub * 8 + i * 32) = make_ushort4(u0, u1, u2, u3);
        }
        xsq += __shfl_xor(xsq, 1, 64);
        xsq += __shfl_xor(xsq, 2, 64);
        if (sub == 0) xsq_s[row] = xsq;
    }

    // ---- xn B-frags (lane cl carries xn row cl) ----
    bfrag xnf[8];
    #pragma unroll
    for (int ks = 0; ks < 8; ++ks)
        xnf[ks] = *(const bfrag*)(smem + cl * 528 + ks * 64 + g * 16);

    // ---- GEMM1: S^T tiles, acc[nt][r] = S[m=cl][k=nt*16+g*4+r] ----
    ffrag acc[32];
    TILE1(b0, 0);  LOADB(b0, 2);
    TILE1(b1, 1);  LOADB(b1, 3);
    TILE1(b0, 2);  LOADB(b0, 4);
    TILE1(b1, 3);  LOADB(b1, 5);
    TILE1(b0, 4);  LOADB(b0, 6);
    TILE1(b1, 5);  LOADB(b1, 7);
    TILE1(b0, 6);  LOADB(b0, 8);
    TILE1(b1, 7);  LOADB(b1, 9);
    TILE1(b0, 8);  LOADB(b0, 10);
    TILE1(b1, 9);  LOADB(b1, 11);
    TILE1(b0, 10); LOADB(b0, 12);
    TILE1(b1, 11); LOADB(b1, 13);
    TILE1(b0, 12); LOADB(b0, 14);
    TILE1(b1, 13); LOADB(b1, 15);
    TILE1(b0, 14); LOADB(b0, 16);
    TILE1(b1, 15); LOADB(b1, 17);
    TILE1(b0, 16); LOADB(b0, 18);
    TILE1(b1, 17); LOADB(b1, 19);
    TILE1(b0, 18); LOADB(b0, 20);
    TILE1(b1, 19); LOADB(b1, 21);
    TILE1(b0, 20); LOADB(b0, 22);
    TILE1(b1, 21); LOADB(b1, 23);
    TILE1(b0, 22); LOADB(b0, 24);
    TILE1(b1, 23); LOADB(b1, 25);
    TILE1(b0, 24); LOADB(b0, 26);
    TILE1(b1, 25); LOADB(b1, 27);
    TILE1(b0, 26); LOADB(b0, 28);
    TILE1(b1, 27); LOADB(b1, 29);
    TILE1(b0, 28); LOADB(b0, 30);
    TILE1(b1, 29); LOADB(b1, 31);
    TILE1(b0, 30);
    TILE1(b1, 31);

    // ---- distances: d = sqrt(xsq + csq - 2*dot); dwordx4 stores ----
    const float xsqv = xsq_s[cl];
    float dsum = 0.f;
    #pragma unroll
    for (int nt = 0; nt < 32; ++nt) {
        f4 cs = *(const f4*)(csq_s + nt * 16 + g * 4);
        f4 dv;
        #pragma unroll
        for (int r = 0; r < 4; ++r) {
            float d2 = xsqv + cs[r] - 2.0f * acc[nt][r];
            dv[r] = sqrtf(fmaxf(d2, 0.0f));
            acc[nt][r] = dv[r];
        }
        *(f4*)(out0 + (size_t)(m0 + cl) * K_CL + nt * 16 + g * 4) = dv;
        dsum += dv[0] + dv[1] + dv[2] + dv[3];
    }
    dsum += __shfl_xor(dsum, 16, 64);
    dsum += __shfl_xor(dsum, 32, 64);
    const float sc = 16384.0f / dsum;   // alpha * K / sum_d

    // ---- prefetch GEMM2 A-tile 0 (hides under exp + out1 phases) ----
    bfrag cA[16], cB[16];
    LOADC(cA, 0);

    // ---- softmax exp + sum (no max-sub: logits ~ -32, f32-safe) ----
    float es = 0.f;
    #pragma unroll
    for (int nt = 0; nt < 32; ++nt)
        #pragma unroll
        for (int r = 0; r < 4; ++r) {
            float p = __expf(-acc[nt][r] * sc);
            acc[nt][r] = p;
            es += p;
        }
    es += __shfl_xor(es, 16, 64);
    es += __shfl_xor(es, 32, 64);
    const float rn = 1.0f / es;

    // ---- assign: dwordx4 store + bf16 into XOR-swizzled LDS ----
    #pragma unroll
    for (int nt = 0; nt < 32; ++nt) {
        f4 av;
        #pragma unroll
        for (int r = 0; r < 4; ++r) av[r] = acc[nt][r] * rn;
        *(f4*)(out1 + (size_t)(m0 + cl) * K_CL + nt * 16 + g * 4) = av;
        unsigned int lo = (unsigned int)f2bf(av[0]) | ((unsigned int)f2bf(av[1]) << 16);
        unsigned int hi = (unsigned int)f2bf(av[2]) | ((unsigned int)f2bf(av[3]) << 16);
        *(uint2*)(smem + ((cl * 1024 + nt * 32 + g * 8) ^ ((cl & 7) << 4))) =
            make_uint2(lo, hi);
    }

    // ---- assign B-frags (lane cl carries assign row cl, k = kt*32+g*8..) ----
    bfrag asf[16];
    #pragma unroll
    for (int kt = 0; kt < 16; ++kt)
        asf[kt] = *(const bfrag*)(smem + ((cl * 1024 + kt * 64 + g * 16) ^ ((cl & 7) << 4)));

    LOADC(cB, 1);

    // ---- GEMM2: x_rec^T tiles, dwordx4 stores ----
    TILE2(cA, 0);  LOADC(cA, 2);
    TILE2(cB, 1);  LOADC(cB, 3);
    TILE2(cA, 2);  LOADC(cA, 4);
    TILE2(cB, 3);  LOADC(cB, 5);
    TILE2(cA, 4);  LOADC(cA, 6);
    TILE2(cB, 5);  LOADC(cB, 7);
    TILE2(cA, 6);  LOADC(cA, 8);
    TILE2(cB, 7);  LOADC(cB, 9);
    TILE2(cA, 8);  LOADC(cA, 10);
    TILE2(cB, 9);  LOADC(cB, 11);
    TILE2(cA, 10); LOADC(cA, 12);
    TILE2(cB, 11); LOADC(cB, 13);
    TILE2(cA, 12); LOADC(cA, 14);
    TILE2(cB, 13); LOADC(cB, 15);
    TILE2(cA, 14);
    TILE2(cB, 15);

#undef LOADB
#undef TILE1
#undef LOADC
#undef TILE2
}

extern "C" void kernel_launch(void* const* d_in, const int* in_sizes, int n_in,
                              void* d_out, int out_size, void* d_ws, size_t ws_size,
                              hipStream_t stream)
{
    const float* x   = (const float*)d_in[0];
    const float* lnw = (const float*)d_in[1];
    const float* lnb = (const float*)d_in[2];
    const float* C   = (const float*)d_in[3];

    float* out0 = (float*)d_out;
    float* out1 = out0 + (size_t)M_ROWS * K_CL;
    float* out2 = out1 + (size_t)M_ROWS * K_CL;

    unsigned short* Cb = (unsigned short*)d_ws;                       // 512*256 bf16
    unsigned short* Ct = Cb + (size_t)K_CL * D_DIM;                   // 256*512 bf16
    float*          cs = (float*)((char*)d_ws + 2u * K_CL * D_DIM * 2u); // [512] f32

    prep_kernel<<<8, 256, 0, stream>>>(C, Cb, Ct, cs);
    fused_kernel<<<M_ROWS / 16, 64, 0, stream>>>(x, lnw, lnb, Cb, Ct, cs,
                                                 out0, out1, out2);
}